// Round 4
// baseline (1597.039 us; speedup 1.0000x reference)
//
#include <hip/hip_runtime.h>
#include <math.h>

// ---------------------------------------------------------------------------
// LongRec.  B=256, S=200, D=U=128, NC=50000.
// alpha = softmax over singleton axis == 1.0 -> h_att = h_d; W_a is dead.
// Pipeline:
//   k0  : 128x128 weights fp32 -> bf16 k-swizzled for MFMA B-frags
//   k12 : MFMA precompute (wave-local LDS, no barriers) -> PRE fp32
//   k3  : 200-step recurrence, 1 wg/row; W columns in REGISTER VECTORS
//         (ext_vector_type(32) x4 — alloca-promote-proof), 2 barriers/step
//   k0b : W_out -> bf16 WT[n][k]  (aliases PRE, dead after k3)
//   k4a : logits = h @ W_out + b_out via bf16 MFMA
//   k4b/c: row stats, softmax normalize
// ---------------------------------------------------------------------------

#define B_  256
#define S_  200
#define U_  128
#define NC  50000
#define NTOK (B_ * S_)       // 51200

// ws layout (in floats)
#define PRE_OFF   0
#define PRE_SZ    (NTOK * 768)            // 39321600 floats
#define LOG_OFF   PRE_SZ                  // logits: 12.8M floats
#define WSWZ_OFF  (PRE_SZ + 12800000)     // bf16 weights: 12*16384 ushort
#define HF_OFF    (PRE_SZ + 13107200)
#define RMAX_OFF  (HF_OFF + B_ * U_)
#define RSUM_OFF  (RMAX_OFF + B_)
// WT (bf16 W_out^T, 50048x128 ushorts = 3.2M floats) aliases PRE_OFF — PRE is
// dead after k3, and k0b runs between k3 and k4a.

// PRE per-token layout: [decay(0) | xr(128) | xz(256) | xh(384) | fdir(512) | psi(640)]

typedef float  float4v  __attribute__((ext_vector_type(4)));
typedef short  short8v  __attribute__((ext_vector_type(8)));
typedef float  f32x32   __attribute__((ext_vector_type(32)));

__device__ __forceinline__ float sigmoidf_(float x) {
    if (x >= 0.f) { return 1.f / (1.f + expf(-x)); }
    float e = expf(x); return e / (1.f + e);
}
__device__ __forceinline__ float softplusf_(float x) {
    return fmaxf(x, 0.f) + log1pf(expf(-fabsf(x)));
}
__device__ __forceinline__ unsigned short f2bf(float f) {   // RNE
    unsigned int u = __float_as_uint(f);
    u = (u + 0x7fffu + ((u >> 16) & 1u)) >> 16;
    return (unsigned short)u;
}
__device__ __forceinline__ unsigned int pack2bf(float a, float b) {
    return (unsigned int)f2bf(a) | ((unsigned int)f2bf(b) << 16);
}
// Barrier draining only LDS (lgkmcnt) — global prefetches stay in flight.
__device__ __forceinline__ void bar_lds() {
    asm volatile("s_waitcnt lgkmcnt(0)\n\ts_barrier" ::: "memory");
}

// ---------------------------------------------------------------------------
// k0: 12 x [128][128] fp32 -> bf16 swizzled  dst[((k>>5)*128 + n)*32 + (k&31)]
__global__ __launch_bounds__(256) void k0_wconv(
    const float* s0, const float* s1, const float* s2, const float* s3,
    const float* s4, const float* s5, const float* s6, const float* s7,
    const float* s8, const float* s9, const float* s10, const float* s11,
    unsigned short* __restrict__ dst)
{
    const float* srcs[12] = { s0,s1,s2,s3,s4,s5,s6,s7,s8,s9,s10,s11 };
    const float* S = srcs[blockIdx.x];
    unsigned short* D = dst + (size_t)blockIdx.x * 16384;
    for (int i = threadIdx.x; i < 16384; i += 256) {
        int k5 = i & 31, n = (i >> 5) & 127, kb = i >> 12;
        D[i] = f2bf(S[(size_t)(kb * 32 + k5) * 128 + n]);
    }
}

// ---------------------------------------------------------------------------
// k0b: W_out [128][50000] fp32 -> WT [n][k] bf16 (rows 50000..50047 left as-is)
__global__ __launch_bounds__(256) void k0b_woutT(const float* __restrict__ W_out,
                                                 unsigned short* __restrict__ WT)
{
    int n  = blockIdx.x * 64 + (threadIdx.x >> 2);
    int k0 = (threadIdx.x & 3) * 32;
    if (n >= NC) return;
#pragma unroll 8
    for (int i = 0; i < 32; ++i)
        WT[(size_t)n * 128 + k0 + i] = f2bf(W_out[(size_t)(k0 + i) * NC + n]);
}

// ---------------------------------------------------------------------------
// MFMA helpers (16x16x32 bf16).  A-frag: lane holds A[m0+(lane&15)][kb*32+quad*8+j].
// B-frag (swizzled W): lane holds W[kb*32+quad*8+j][nt*16+(lane&15)].
// C/D: col = lane&15, row = quad*4 + reg.
__device__ __forceinline__ void gemm_k128(const unsigned short (*A)[136],
                                          int m0, int l16, int quad,
                                          const unsigned short* __restrict__ Wm,
                                          float4v acc[8]) {
#pragma unroll
    for (int kb = 0; kb < 4; ++kb) {
        short8v av = *(const short8v*)&A[m0 + l16][kb * 32 + quad * 8];
#pragma unroll
        for (int nt = 0; nt < 8; ++nt) {
            short8v bv = *(const short8v*)(Wm + (((kb * 128) + nt * 16 + l16) * 32 + quad * 8));
            acc[nt] = __builtin_amdgcn_mfma_f32_16x16x32_bf16(av, bv, acc[nt], 0, 0, 0);
        }
    }
}
__device__ __forceinline__ void zero8(float4v acc[8]) {
#pragma unroll
    for (int i = 0; i < 8; ++i) acc[i] = (float4v)0.0f;
}

// ---------------------------------------------------------------------------
// k12: fused MFMA precompute.  grid = NTOK/64, block = 256 (4 waves).
__global__ __launch_bounds__(256) void k12_precompute(
    const int* __restrict__ item, const int* __restrict__ tix, const int* __restrict__ frq,
    const float* __restrict__ Ei, const float* __restrict__ Et, const float* __restrict__ Ef,
    const float* __restrict__ b_r, const float* __restrict__ b_z, const float* __restrict__ b_h,
    const float* __restrict__ b_tg, const float* __restrict__ b_fg,
    const float* __restrict__ b_delta, const float* __restrict__ b_f_dir, const float* __restrict__ b_psi,
    const unsigned short* __restrict__ WZ,
    float* __restrict__ PRE)
{
    __shared__ unsigned short Axi[64][136];   // xi
    __shared__ unsigned short Axb[64][136];   // xt -> tg
    __shared__ unsigned short Axc[64][136];   // xf -> fg

    const int t0  = blockIdx.x * 64;
    const int tid = threadIdx.x;

    // Staging: rows are WAVE-LOCAL (wave w stages rows 16w..16w+15 and only
    // ever reads/writes those rows => no barriers needed in this kernel).
    {
        const int row  = tid >> 2;
        const int part = tid & 3;
        const int tok  = t0 + row;
        const float* pei = Ei + (size_t)item[tok] * U_ + part * 32;
        const float* pet = Et + (size_t)tix[tok]  * U_ + part * 32;
        const float* pef = Ef + (size_t)frq[tok]  * U_ + part * 32;
#pragma unroll
        for (int i = 0; i < 8; ++i) {
            float4 v = *(const float4*)(pei + i * 4);
            *(uint2*)&Axi[row][part * 32 + i * 4] = make_uint2(pack2bf(v.x, v.y), pack2bf(v.z, v.w));
            v = *(const float4*)(pet + i * 4);
            *(uint2*)&Axb[row][part * 32 + i * 4] = make_uint2(pack2bf(v.x, v.y), pack2bf(v.z, v.w));
            v = *(const float4*)(pef + i * 4);
            *(uint2*)&Axc[row][part * 32 + i * 4] = make_uint2(pack2bf(v.x, v.y), pack2bf(v.z, v.w));
        }
    }

    const int lane = tid & 63;
    const int wid  = tid >> 6;
    const int quad = lane >> 4;
    const int l16  = lane & 15;
    const int m0   = wid * 16;

    const unsigned short* WM0  = WZ;                 // W_xtg
    const unsigned short* WM1  = WZ + 1  * 16384;    // W_tg
    const unsigned short* WM2  = WZ + 2  * 16384;    // W_xfg
    const unsigned short* WM3  = WZ + 3  * 16384;    // W_fg
    const unsigned short* WM4  = WZ + 4  * 16384;    // W_xr
    const unsigned short* WM5  = WZ + 5  * 16384;    // W_xz
    const unsigned short* WM6  = WZ + 6  * 16384;    // W_xh
    const unsigned short* WM7  = WZ + 7  * 16384;    // W_delta top (tg rows)
    const unsigned short* WM8  = WZ + 8  * 16384;    // W_delta bot (fg rows)
    const unsigned short* WM9  = WZ + 9  * 16384;    // W_f_dir
    const unsigned short* WM10 = WZ + 10 * 16384;    // W_psi

    float4v acc[8];

    // ---- tg = sigmoid(xi@W_xtg + xt@W_tg + b_tg) -> Axb (bf16, A-layout) ----
    zero8(acc);
    gemm_k128(Axi, m0, l16, quad, WM0, acc);
    gemm_k128(Axb, m0, l16, quad, WM1, acc);
#pragma unroll
    for (int nt = 0; nt < 8; ++nt) {
        int n = nt * 16 + l16;
        float bb = b_tg[n];
#pragma unroll
        for (int r = 0; r < 4; ++r)
            Axb[m0 + quad * 4 + r][n] = f2bf(sigmoidf_(acc[nt][r] + bb));
    }
    // ---- fg = sigmoid(xi@W_xfg + xf@W_fg + b_fg) -> Axc ----
    zero8(acc);
    gemm_k128(Axi, m0, l16, quad, WM2, acc);
    gemm_k128(Axc, m0, l16, quad, WM3, acc);
#pragma unroll
    for (int nt = 0; nt < 8; ++nt) {
        int n = nt * 16 + l16;
        float bb = b_fg[n];
#pragma unroll
        for (int r = 0; r < 4; ++r)
            Axc[m0 + quad * 4 + r][n] = f2bf(sigmoidf_(acc[nt][r] + bb));
    }

    const int tokbase = t0 + m0 + quad * 4;

    // ---- xr, xz, xh ----
    {
        const unsigned short* Wx[3] = { WM4, WM5, WM6 };
        const float* bx[3] = { b_r, b_z, b_h };
        const int    off[3] = { 128, 256, 384 };
#pragma unroll
        for (int m = 0; m < 3; ++m) {
            zero8(acc);
            gemm_k128(Axi, m0, l16, quad, Wx[m], acc);
#pragma unroll
            for (int nt = 0; nt < 8; ++nt) {
                int n = nt * 16 + l16;
                float bb = bx[m][n];
#pragma unroll
                for (int r = 0; r < 4; ++r)
                    PRE[(size_t)(tokbase + r) * 768 + off[m] + n] = acc[nt][r] + bb;
            }
        }
    }
    // ---- decay = exp(-softplus([tg|fg]@W_delta + b_delta)) ----
    zero8(acc);
    gemm_k128(Axb, m0, l16, quad, WM7, acc);
    gemm_k128(Axc, m0, l16, quad, WM8, acc);
#pragma unroll
    for (int nt = 0; nt < 8; ++nt) {
        int n = nt * 16 + l16;
        float bb = b_delta[n];
#pragma unroll
        for (int r = 0; r < 4; ++r)
            PRE[(size_t)(tokbase + r) * 768 + 0 + n] = expf(-softplusf_(acc[nt][r] + bb));
    }
    // ---- fdir = fg@W_f_dir + b ----
    zero8(acc);
    gemm_k128(Axc, m0, l16, quad, WM9, acc);
#pragma unroll
    for (int nt = 0; nt < 8; ++nt) {
        int n = nt * 16 + l16;
        float bb = b_f_dir[n];
#pragma unroll
        for (int r = 0; r < 4; ++r)
            PRE[(size_t)(tokbase + r) * 768 + 512 + n] = acc[nt][r] + bb;
    }
    // ---- psi = sigmoid(fg@W_psi + b) ----
    zero8(acc);
    gemm_k128(Axc, m0, l16, quad, WM10, acc);
#pragma unroll
    for (int nt = 0; nt < 8; ++nt) {
        int n = nt * 16 + l16;
        float bb = b_psi[n];
#pragma unroll
        for (int r = 0; r < 4; ++r)
            PRE[(size_t)(tokbase + r) * 768 + 640 + n] = sigmoidf_(acc[nt][r] + bb);
    }
}

// ---------------------------------------------------------------------------
// k3: one workgroup per batch row, 384 threads (g0: W_hr, g1: W_hz, g2: W_hh).
// Weight column lives in 4x f32x32 REGISTER VECTORS (SSA values — cannot be
// demoted to scratch, unlike a float[128] alloca; R3 showed VGPR=112 => spill).
// 2 barriers/step: g2 produces both h and hd(next) in its phase.
__global__ __launch_bounds__(384, 2) void k3_scan(
    const float* __restrict__ PRE,
    const float* __restrict__ W_hr, const float* __restrict__ W_hz, const float* __restrict__ W_hh,
    unsigned short* __restrict__ Hb)
{
    const int b = blockIdx.x;
    const int tid = threadIdx.x;
    const int g = tid >> 7;      // 0,1,2
    const int u = tid & 127;

    const float* W = (g == 0) ? W_hr : ((g == 1) ? W_hz : W_hh);
    f32x32 wc0, wc1, wc2, wc3;
#pragma unroll
    for (int k = 0; k < 32; ++k) {
        wc0[k] = W[(size_t)(k      ) * U_ + u];
        wc1[k] = W[(size_t)(k +  32) * U_ + u];
        wc2[k] = W[(size_t)(k +  64) * U_ + u];
        wc3[k] = W[(size_t)(k +  96) * U_ + u];
    }

    __shared__ __align__(16) float h[U_];
    __shared__ __align__(16) float hd[U_];
    __shared__ __align__(16) float rh[U_];
    __shared__ __align__(16) float zb[U_];
    if (tid < U_) { h[tid] = 0.f; hd[tid] = 0.f; }   // h0 = 0 -> hd(step0) = 0

    const float* pre = PRE + (size_t)b * S_ * 768;
    float c0 = 0.f, c1 = 0.f, c2 = 0.f, c3 = 0.f;
    {
        const float* p = pre;
        if (g == 0)      { c0 = p[128 + u]; }                       // xr[0]
        else if (g == 1) { c0 = p[256 + u]; }                       // xz[0]
        else             { c0 = p[384 + u]; c1 = p[512 + u];        // xh, fdir
                           c2 = p[640 + u];                         // psi
                           c3 = pre[768 + u]; }                     // decay[1]
    }
    bar_lds();

    for (int s = 0; s < S_; ++s) {
        // prefetch step s+1 (left in flight across both barriers)
        float n0 = 0.f, n1 = 0.f, n2 = 0.f, n3 = 0.f;
        if (s + 1 < S_) {
            const float* p = pre + (size_t)(s + 1) * 768;
            if (g == 0)      { n0 = p[128 + u]; }
            else if (g == 1) { n0 = p[256 + u]; }
            else             { n0 = p[384 + u]; n1 = p[512 + u]; n2 = p[640 + u];
                               n3 = (s + 2 < S_) ? pre[(size_t)(s + 2) * 768 + u] : 0.f; }
        }

        // Phase B: g0 -> r, rh;  g1 -> z
        if (g < 2) {
            float a0 = 0.f, a1 = 0.f, a2 = 0.f, a3 = 0.f;
#pragma unroll
            for (int half = 0; half < 4; ++half) {
                const f32x32& w = (half == 0) ? wc0 : (half == 1) ? wc1 : (half == 2) ? wc2 : wc3;
#pragma unroll
                for (int kk = 0; kk < 8; ++kk) {
                    float4 hv = *(const float4*)&hd[half * 32 + kk * 4];
                    a0 = fmaf(hv.x, w[4 * kk + 0], a0);
                    a1 = fmaf(hv.y, w[4 * kk + 1], a1);
                    a2 = fmaf(hv.z, w[4 * kk + 2], a2);
                    a3 = fmaf(hv.w, w[4 * kk + 3], a3);
                }
            }
            float mv = (a0 + a1) + (a2 + a3);
            if (g == 0) {
                float r = sigmoidf_(c0 + mv);
                rh[u] = r * hd[u];
            } else {
                zb[u] = sigmoidf_(c0 + mv);
            }
        }
        bar_lds();   // rh, zb ready

        // Phase C: g2 -> h_new and hd(next)
        if (g == 2) {
            float a0 = 0.f, a1 = 0.f, a2 = 0.f, a3 = 0.f;
#pragma unroll
            for (int half = 0; half < 4; ++half) {
                const f32x32& w = (half == 0) ? wc0 : (half == 1) ? wc1 : (half == 2) ? wc2 : wc3;
#pragma unroll
                for (int kk = 0; kk < 8; ++kk) {
                    float4 hv = *(const float4*)&rh[half * 32 + kk * 4];
                    a0 = fmaf(hv.x, w[4 * kk + 0], a0);
                    a1 = fmaf(hv.y, w[4 * kk + 1], a1);
                    a2 = fmaf(hv.z, w[4 * kk + 2], a2);
                    a3 = fmaf(hv.w, w[4 * kk + 3], a3);
                }
            }
            float mv2 = (a0 + a1) + (a2 + a3);
            float hb = tanhf(c0 + mv2);
            float hf = tanhf(hb + c1);
            float hc = (1.f - c2) * hb + c2 * hf;
            float z  = zb[u];
            float hn = (1.f - z) * hd[u] + z * hc;   // alpha==1 -> h_att = h_d
            h[u]  = hn;
            hd[u] = c3 * hn;                          // decay[s+1] * h  (next step's h_d)
        }
        bar_lds();   // h, hd ready for next step

        c0 = n0; c1 = n1; c2 = n2; c3 = n3;
    }
    if (tid < U_) Hb[(size_t)b * U_ + tid] = f2bf(h[tid]);
}

// ---------------------------------------------------------------------------
// k4a: logits = h @ W_out + b_out via bf16 MFMA.
// grid (ceil(NC/128), 4); block 256 = 4 waves; wave w: rows blockIdx.y*64+16w.
__global__ __launch_bounds__(256) void k4a_logits(
    const unsigned short* __restrict__ Hb, const unsigned short* __restrict__ WT,
    const float* __restrict__ b_out, float* __restrict__ logits)
{
    const int tid  = threadIdx.x;
    const int lane = tid & 63, wid = tid >> 6;
    const int quad = lane >> 4, l16 = lane & 15;
    const int rb = blockIdx.y * 64 + wid * 16;
    const int cb = blockIdx.x * 128;

    short8v av[4];
#pragma unroll
    for (int kb = 0; kb < 4; ++kb)
        av[kb] = *(const short8v*)&Hb[(size_t)(rb + l16) * 128 + kb * 32 + quad * 8];

    float4v acc[8];
#pragma unroll
    for (int i = 0; i < 8; ++i) acc[i] = (float4v)0.0f;

#pragma unroll
    for (int kb = 0; kb < 4; ++kb) {
#pragma unroll
        for (int nt = 0; nt < 8; ++nt) {
            short8v bv = *(const short8v*)&WT[(size_t)(cb + nt * 16 + l16) * 128 + kb * 32 + quad * 8];
            acc[nt] = __builtin_amdgcn_mfma_f32_16x16x32_bf16(av[kb], bv, acc[nt], 0, 0, 0);
        }
    }
#pragma unroll
    for (int nt = 0; nt < 8; ++nt) {
        int n = cb + nt * 16 + l16;
        if (n < NC) {
            float bb = b_out[n];
#pragma unroll
            for (int r = 0; r < 4; ++r)
                logits[(size_t)(rb + quad * 4 + r) * NC + n] = acc[nt][r] + bb;
        }
    }
}

// ---------------------------------------------------------------------------
__global__ __launch_bounds__(256) void k4b_rowstats(
    const float* __restrict__ logits, float* __restrict__ rmax, float* __restrict__ rsum)
{
    const int r = blockIdx.x;
    const int tid = threadIdx.x;
    const float* row = logits + (size_t)r * NC;

    float m = -INFINITY, s = 0.f;
    for (int c = tid; c < NC; c += 256) {
        float x = row[c];
        float mn = fmaxf(m, x);
        s = s * expf(m - mn) + expf(x - mn);
        m = mn;
    }
    __shared__ float sm[256], ss[256];
    sm[tid] = m; ss[tid] = s;
    __syncthreads();
    for (int off = 128; off > 0; off >>= 1) {
        if (tid < off) {
            float m2 = sm[tid + off], s2 = ss[tid + off];
            float M = fmaxf(sm[tid], m2);
            ss[tid] = ss[tid] * expf(sm[tid] - M) + s2 * expf(m2 - M);
            sm[tid] = M;
        }
        __syncthreads();
    }
    if (tid == 0) { rmax[r] = sm[0]; rsum[r] = ss[0]; }
}

__global__ __launch_bounds__(256) void k4c_norm(
    const float* __restrict__ logits, const float* __restrict__ rmax,
    const float* __restrict__ rsum, float* __restrict__ out)
{
    const int r = blockIdx.y;
    const int c = blockIdx.x * 256 + threadIdx.x;
    if (c < NC) {
        size_t i = (size_t)r * NC + c;
        out[i] = expf(logits[i] - rmax[r]) / rsum[r];
    }
}

// ---------------------------------------------------------------------------
extern "C" void kernel_launch(void* const* d_in, const int* in_sizes, int n_in,
                              void* d_out, int out_size, void* d_ws, size_t ws_size,
                              hipStream_t stream) {
    const int*   item   = (const int*)d_in[0];
    const int*   tix    = (const int*)d_in[1];
    const int*   frq    = (const int*)d_in[2];
    const float* Ei     = (const float*)d_in[3];
    const float* Et     = (const float*)d_in[4];
    const float* Ef     = (const float*)d_in[5];
    const float* W_xr   = (const float*)d_in[6];
    const float* W_hr   = (const float*)d_in[7];
    const float* b_r    = (const float*)d_in[8];
    const float* W_xz   = (const float*)d_in[9];
    const float* W_hz   = (const float*)d_in[10];
    const float* b_z    = (const float*)d_in[11];
    const float* W_xh   = (const float*)d_in[12];
    const float* W_hh   = (const float*)d_in[13];
    const float* b_h    = (const float*)d_in[14];
    const float* W_xtg  = (const float*)d_in[15];
    const float* W_tg   = (const float*)d_in[16];
    const float* b_tg   = (const float*)d_in[17];
    const float* W_xfg  = (const float*)d_in[18];
    const float* W_fg   = (const float*)d_in[19];
    const float* b_fg   = (const float*)d_in[20];
    const float* W_delta= (const float*)d_in[21];
    const float* b_delta= (const float*)d_in[22];
    const float* W_f_dir= (const float*)d_in[23];
    const float* b_f_dir= (const float*)d_in[24];
    const float* W_psi  = (const float*)d_in[25];
    const float* b_psi  = (const float*)d_in[26];
    // d_in[27] = W_a — dead (softmax over singleton axis == 1)
    const float* W_out  = (const float*)d_in[28];
    const float* b_out  = (const float*)d_in[29];
    float* out = (float*)d_out;

    float* ws   = (float*)d_ws;
    float* PRE  = ws + PRE_OFF;
    float* LOG  = ws + LOG_OFF;
    unsigned short* WSWZ = (unsigned short*)(ws + WSWZ_OFF);
    unsigned short* WT   = (unsigned short*)(ws + PRE_OFF);   // aliases PRE (dead after k3)
    unsigned short* Hb   = (unsigned short*)(ws + HF_OFF);
    float* RMAX = ws + RMAX_OFF;
    float* RSUM = ws + RSUM_OFF;

    k0_wconv<<<12, 256, 0, stream>>>(
        W_xtg, W_tg, W_xfg, W_fg, W_xr, W_xz, W_xh,
        W_delta, W_delta + 128 * 128, W_f_dir, W_psi,
        W_psi /* pad slot 11, unused by k12 */, WSWZ);
    k12_precompute<<<NTOK / 64, 256, 0, stream>>>(
        item, tix, frq, Ei, Et, Ef,
        b_r, b_z, b_h, b_tg, b_fg, b_delta, b_f_dir, b_psi,
        WSWZ, PRE);
    k3_scan<<<B_, 384, 0, stream>>>(PRE, W_hr, W_hz, W_hh, Hb);
    k0b_woutT<<<(NC + 63) / 64, 256, 0, stream>>>(W_out, WT);
    k4a_logits<<<dim3((NC + 127) / 128, B_ / 64), 256, 0, stream>>>(Hb, WT, b_out, LOG);
    k4b_rowstats<<<B_, 256, 0, stream>>>(LOG, RMAX, RSUM);
    k4c_norm<<<dim3((NC + 255) / 256, B_), 256, 0, stream>>>(LOG, RMAX, RSUM, out);
}

// Round 5
// 887.683 us; speedup vs baseline: 1.7991x; 1.7991x over previous
//
#include <hip/hip_runtime.h>
#include <math.h>

// ---------------------------------------------------------------------------
// LongRec.  B=256, S=200, D=U=128, NC=50000.
// alpha = softmax over singleton axis == 1.0 -> h_att = h_d; W_a is dead.
// Pipeline:
//   k0  : 128x128 weights fp32 -> bf16 k-swizzled for MFMA B-frags
//   k12 : MFMA precompute (wave-local LDS, no barriers) -> PRE fp32
//   k3  : 200-step recurrence, 1 wg/row, 768 thr = 6 grps x 128;
//         64 weights/thread pinned in VGPRs via opaque asm (R4's 128/thread
//         spilled: WRITE_SIZE 32MB). 4 lgkm-only barriers/step.
//   k0b : W_out -> bf16 WT[n][k]  (aliases PRE, dead after k3)
//   k4a : logits = h @ W_out + b_out via bf16 MFMA
//   k4b/c: row stats, softmax normalize
// ---------------------------------------------------------------------------

#define B_  256
#define S_  200
#define U_  128
#define NC  50000
#define NTOK (B_ * S_)       // 51200

// ws layout (in floats)
#define PRE_OFF   0
#define PRE_SZ    (NTOK * 768)            // 39321600 floats
#define LOG_OFF   PRE_SZ                  // logits: 12.8M floats
#define WSWZ_OFF  (PRE_SZ + 12800000)     // bf16 weights: 12*16384 ushort
#define HF_OFF    (PRE_SZ + 13107200)
#define RMAX_OFF  (HF_OFF + B_ * U_)
#define RSUM_OFF  (RMAX_OFF + B_)
// WT (bf16 W_out^T) aliases PRE_OFF — PRE dead after k3; k0b runs after k3.

// PRE per-token layout: [decay(0) | xr(128) | xz(256) | xh(384) | fdir(512) | psi(640)]

typedef float  float4v  __attribute__((ext_vector_type(4)));
typedef short  short8v  __attribute__((ext_vector_type(8)));

__device__ __forceinline__ float sigmoidf_(float x) {
    if (x >= 0.f) { return 1.f / (1.f + expf(-x)); }
    float e = expf(x); return e / (1.f + e);
}
__device__ __forceinline__ float softplusf_(float x) {
    return fmaxf(x, 0.f) + log1pf(expf(-fabsf(x)));
}
__device__ __forceinline__ unsigned short f2bf(float f) {   // RNE
    unsigned int u = __float_as_uint(f);
    u = (u + 0x7fffu + ((u >> 16) & 1u)) >> 16;
    return (unsigned short)u;
}
__device__ __forceinline__ unsigned int pack2bf(float a, float b) {
    return (unsigned int)f2bf(a) | ((unsigned int)f2bf(b) << 16);
}
// Barrier draining only LDS (lgkmcnt) — global prefetches stay in flight.
__device__ __forceinline__ void bar_lds() {
    asm volatile("s_waitcnt lgkmcnt(0)\n\ts_barrier" ::: "memory");
}

// ---------------------------------------------------------------------------
// k0: 12 x [128][128] fp32 -> bf16 swizzled  dst[((k>>5)*128 + n)*32 + (k&31)]
__global__ __launch_bounds__(256) void k0_wconv(
    const float* s0, const float* s1, const float* s2, const float* s3,
    const float* s4, const float* s5, const float* s6, const float* s7,
    const float* s8, const float* s9, const float* s10, const float* s11,
    unsigned short* __restrict__ dst)
{
    const float* srcs[12] = { s0,s1,s2,s3,s4,s5,s6,s7,s8,s9,s10,s11 };
    const float* S = srcs[blockIdx.x];
    unsigned short* D = dst + (size_t)blockIdx.x * 16384;
    for (int i = threadIdx.x; i < 16384; i += 256) {
        int k5 = i & 31, n = (i >> 5) & 127, kb = i >> 12;
        D[i] = f2bf(S[(size_t)(kb * 32 + k5) * 128 + n]);
    }
}

// ---------------------------------------------------------------------------
// k0b: W_out [128][50000] fp32 -> WT [n][k] bf16
__global__ __launch_bounds__(256) void k0b_woutT(const float* __restrict__ W_out,
                                                 unsigned short* __restrict__ WT)
{
    int n  = blockIdx.x * 64 + (threadIdx.x >> 2);
    int k0 = (threadIdx.x & 3) * 32;
    if (n >= NC) return;
#pragma unroll 8
    for (int i = 0; i < 32; ++i)
        WT[(size_t)n * 128 + k0 + i] = f2bf(W_out[(size_t)(k0 + i) * NC + n]);
}

// ---------------------------------------------------------------------------
// MFMA helpers (16x16x32 bf16).  A-frag: lane holds A[m0+(lane&15)][kb*32+quad*8+j].
// B-frag (swizzled W): lane holds W[kb*32+quad*8+j][nt*16+(lane&15)].
// C/D: col = lane&15, row = quad*4 + reg.
__device__ __forceinline__ void gemm_k128(const unsigned short (*A)[136],
                                          int m0, int l16, int quad,
                                          const unsigned short* __restrict__ Wm,
                                          float4v acc[8]) {
#pragma unroll
    for (int kb = 0; kb < 4; ++kb) {
        short8v av = *(const short8v*)&A[m0 + l16][kb * 32 + quad * 8];
#pragma unroll
        for (int nt = 0; nt < 8; ++nt) {
            short8v bv = *(const short8v*)(Wm + (((kb * 128) + nt * 16 + l16) * 32 + quad * 8));
            acc[nt] = __builtin_amdgcn_mfma_f32_16x16x32_bf16(av, bv, acc[nt], 0, 0, 0);
        }
    }
}
__device__ __forceinline__ void zero8(float4v acc[8]) {
#pragma unroll
    for (int i = 0; i < 8; ++i) acc[i] = (float4v)0.0f;
}

// ---------------------------------------------------------------------------
// k12: fused MFMA precompute.  grid = NTOK/64, block = 256 (4 waves).
__global__ __launch_bounds__(256) void k12_precompute(
    const int* __restrict__ item, const int* __restrict__ tix, const int* __restrict__ frq,
    const float* __restrict__ Ei, const float* __restrict__ Et, const float* __restrict__ Ef,
    const float* __restrict__ b_r, const float* __restrict__ b_z, const float* __restrict__ b_h,
    const float* __restrict__ b_tg, const float* __restrict__ b_fg,
    const float* __restrict__ b_delta, const float* __restrict__ b_f_dir, const float* __restrict__ b_psi,
    const unsigned short* __restrict__ WZ,
    float* __restrict__ PRE)
{
    __shared__ unsigned short Axi[64][136];   // xi
    __shared__ unsigned short Axb[64][136];   // xt -> tg
    __shared__ unsigned short Axc[64][136];   // xf -> fg

    const int t0  = blockIdx.x * 64;
    const int tid = threadIdx.x;

    // Staging: rows are WAVE-LOCAL (wave w stages rows 16w..16w+15 and only
    // ever reads/writes those rows => no barriers needed in this kernel).
    {
        const int row  = tid >> 2;
        const int part = tid & 3;
        const int tok  = t0 + row;
        const float* pei = Ei + (size_t)item[tok] * U_ + part * 32;
        const float* pet = Et + (size_t)tix[tok]  * U_ + part * 32;
        const float* pef = Ef + (size_t)frq[tok]  * U_ + part * 32;
#pragma unroll
        for (int i = 0; i < 8; ++i) {
            float4 v = *(const float4*)(pei + i * 4);
            *(uint2*)&Axi[row][part * 32 + i * 4] = make_uint2(pack2bf(v.x, v.y), pack2bf(v.z, v.w));
            v = *(const float4*)(pet + i * 4);
            *(uint2*)&Axb[row][part * 32 + i * 4] = make_uint2(pack2bf(v.x, v.y), pack2bf(v.z, v.w));
            v = *(const float4*)(pef + i * 4);
            *(uint2*)&Axc[row][part * 32 + i * 4] = make_uint2(pack2bf(v.x, v.y), pack2bf(v.z, v.w));
        }
    }

    const int lane = tid & 63;
    const int wid  = tid >> 6;
    const int quad = lane >> 4;
    const int l16  = lane & 15;
    const int m0   = wid * 16;

    const unsigned short* WM0  = WZ;                 // W_xtg
    const unsigned short* WM1  = WZ + 1  * 16384;    // W_tg
    const unsigned short* WM2  = WZ + 2  * 16384;    // W_xfg
    const unsigned short* WM3  = WZ + 3  * 16384;    // W_fg
    const unsigned short* WM4  = WZ + 4  * 16384;    // W_xr
    const unsigned short* WM5  = WZ + 5  * 16384;    // W_xz
    const unsigned short* WM6  = WZ + 6  * 16384;    // W_xh
    const unsigned short* WM7  = WZ + 7  * 16384;    // W_delta top (tg rows)
    const unsigned short* WM8  = WZ + 8  * 16384;    // W_delta bot (fg rows)
    const unsigned short* WM9  = WZ + 9  * 16384;    // W_f_dir
    const unsigned short* WM10 = WZ + 10 * 16384;    // W_psi

    float4v acc[8];

    // ---- tg = sigmoid(xi@W_xtg + xt@W_tg + b_tg) -> Axb (bf16, A-layout) ----
    zero8(acc);
    gemm_k128(Axi, m0, l16, quad, WM0, acc);
    gemm_k128(Axb, m0, l16, quad, WM1, acc);
#pragma unroll
    for (int nt = 0; nt < 8; ++nt) {
        int n = nt * 16 + l16;
        float bb = b_tg[n];
#pragma unroll
        for (int r = 0; r < 4; ++r)
            Axb[m0 + quad * 4 + r][n] = f2bf(sigmoidf_(acc[nt][r] + bb));
    }
    // ---- fg = sigmoid(xi@W_xfg + xf@W_fg + b_fg) -> Axc ----
    zero8(acc);
    gemm_k128(Axi, m0, l16, quad, WM2, acc);
    gemm_k128(Axc, m0, l16, quad, WM3, acc);
#pragma unroll
    for (int nt = 0; nt < 8; ++nt) {
        int n = nt * 16 + l16;
        float bb = b_fg[n];
#pragma unroll
        for (int r = 0; r < 4; ++r)
            Axc[m0 + quad * 4 + r][n] = f2bf(sigmoidf_(acc[nt][r] + bb));
    }

    const int tokbase = t0 + m0 + quad * 4;

    // ---- xr, xz, xh ----
    {
        const unsigned short* Wx[3] = { WM4, WM5, WM6 };
        const float* bx[3] = { b_r, b_z, b_h };
        const int    off[3] = { 128, 256, 384 };
#pragma unroll
        for (int m = 0; m < 3; ++m) {
            zero8(acc);
            gemm_k128(Axi, m0, l16, quad, Wx[m], acc);
#pragma unroll
            for (int nt = 0; nt < 8; ++nt) {
                int n = nt * 16 + l16;
                float bb = bx[m][n];
#pragma unroll
                for (int r = 0; r < 4; ++r)
                    PRE[(size_t)(tokbase + r) * 768 + off[m] + n] = acc[nt][r] + bb;
            }
        }
    }
    // ---- decay = exp(-softplus([tg|fg]@W_delta + b_delta)) ----
    zero8(acc);
    gemm_k128(Axb, m0, l16, quad, WM7, acc);
    gemm_k128(Axc, m0, l16, quad, WM8, acc);
#pragma unroll
    for (int nt = 0; nt < 8; ++nt) {
        int n = nt * 16 + l16;
        float bb = b_delta[n];
#pragma unroll
        for (int r = 0; r < 4; ++r)
            PRE[(size_t)(tokbase + r) * 768 + 0 + n] = expf(-softplusf_(acc[nt][r] + bb));
    }
    // ---- fdir = fg@W_f_dir + b ----
    zero8(acc);
    gemm_k128(Axc, m0, l16, quad, WM9, acc);
#pragma unroll
    for (int nt = 0; nt < 8; ++nt) {
        int n = nt * 16 + l16;
        float bb = b_f_dir[n];
#pragma unroll
        for (int r = 0; r < 4; ++r)
            PRE[(size_t)(tokbase + r) * 768 + 512 + n] = acc[nt][r] + bb;
    }
    // ---- psi = sigmoid(fg@W_psi + b) ----
    zero8(acc);
    gemm_k128(Axc, m0, l16, quad, WM10, acc);
#pragma unroll
    for (int nt = 0; nt < 8; ++nt) {
        int n = nt * 16 + l16;
        float bb = b_psi[n];
#pragma unroll
        for (int r = 0; r < 4; ++r)
            PRE[(size_t)(tokbase + r) * 768 + 640 + n] = sigmoidf_(acc[nt][r] + bb);
    }
}

// ---------------------------------------------------------------------------
// k3: one workgroup per batch row; 768 threads = 6 groups of 128.
//   grp 0,1 : W_hr k-halves    grp 2,3 : W_hz    grp 4,5 : W_hh
// Each thread holds 64 loop-invariant weights, pinned into VGPRs by an
// opaque asm (defeats the load-sinking seen in R2/R3 and the vector spill
// seen in R4).  Step: B(partials) / B2(combine r,z) / C(partials) /
// C2(h update) with lgkm-only barriers; PRE prefetch stays in vmcnt flight.
__global__ __launch_bounds__(768, 2) void k3_scan(
    const float* __restrict__ PRE,
    const float* __restrict__ W_hr, const float* __restrict__ W_hz, const float* __restrict__ W_hh,
    unsigned short* __restrict__ Hb)
{
    const int b    = blockIdx.x;
    const int tid  = threadIdx.x;
    const int grp  = tid >> 7;      // 0..5
    const int u    = tid & 127;
    const int half = grp & 1;       // which 64-element k-half
    const int mat  = grp >> 1;      // 0: W_hr, 1: W_hz, 2: W_hh

    const float* W = (mat == 0) ? W_hr : ((mat == 1) ? W_hz : W_hh);
    const int kb0 = half * 64;
    float wc[64];
#pragma unroll
    for (int k = 0; k < 64; ++k) wc[k] = W[(size_t)(kb0 + k) * U_ + u];
#pragma unroll
    for (int k = 0; k < 64; ++k) asm volatile("" : "+v"(wc[k]));   // pin in VGPRs

    __shared__ __align__(16) float hd[U_];
    __shared__ __align__(16) float rh[U_];
    __shared__ __align__(16) float zb[U_];
    __shared__ __align__(16) float pr[2][U_];
    __shared__ __align__(16) float pz[2][U_];
    __shared__ __align__(16) float ph[2][U_];
    if (tid < U_) hd[tid] = 0.f;    // h0 = 0 -> h_d(step 0) = 0

    const float* pre = PRE + (size_t)b * S_ * 768;
    // loop-carried per-group scalars (c*) and h state (grp 4 only)
    float c0 = 0.f, c1 = 0.f, c2 = 0.f, c3 = 0.f, hn = 0.f;
    {
        const float* p = pre;
        if (grp == 0)      c0 = p[128 + u];                          // xr[0]
        else if (grp == 2) c0 = p[256 + u];                          // xz[0]
        else if (grp == 4) { c0 = p[384 + u]; c1 = p[512 + u];       // xh, fdir
                             c2 = p[640 + u];                        // psi
                             c3 = pre[768 + u]; }                    // decay[1]
    }
    bar_lds();

    for (int s = 0; s < S_; ++s) {
        // prefetch step s+1 (left in vmcnt flight across all 4 barriers)
        float n0 = 0.f, n1 = 0.f, n2 = 0.f, n3 = 0.f;
        if (s + 1 < S_) {
            const float* p = pre + (size_t)(s + 1) * 768;
            if (grp == 0)      n0 = p[128 + u];
            else if (grp == 2) n0 = p[256 + u];
            else if (grp == 4) { n0 = p[384 + u]; n1 = p[512 + u]; n2 = p[640 + u];
                                 n3 = (s + 2 < S_) ? pre[(size_t)(s + 2) * 768 + u] : 0.f; }
        }

        // Phase B: r- and z-matvec partials over hd
        if (mat < 2) {
            float a0 = 0.f, a1 = 0.f, a2 = 0.f, a3 = 0.f;
#pragma unroll
            for (int kk = 0; kk < 16; ++kk) {
                float4 hv = *(const float4*)&hd[kb0 + kk * 4];
                a0 = fmaf(hv.x, wc[4 * kk + 0], a0);
                a1 = fmaf(hv.y, wc[4 * kk + 1], a1);
                a2 = fmaf(hv.z, wc[4 * kk + 2], a2);
                a3 = fmaf(hv.w, wc[4 * kk + 3], a3);
            }
            float p = (a0 + a1) + (a2 + a3);
            if (mat == 0) pr[half][u] = p; else pz[half][u] = p;
        }
        bar_lds();   // pr, pz ready

        // Phase B2: combine
        if (grp == 0)      rh[u] = sigmoidf_(c0 + pr[0][u] + pr[1][u]) * hd[u];
        else if (grp == 2) zb[u] = sigmoidf_(c0 + pz[0][u] + pz[1][u]);
        bar_lds();   // rh, zb ready

        // Phase C: h-matvec partials over rh
        if (mat == 2) {
            float a0 = 0.f, a1 = 0.f, a2 = 0.f, a3 = 0.f;
#pragma unroll
            for (int kk = 0; kk < 16; ++kk) {
                float4 hv = *(const float4*)&rh[kb0 + kk * 4];
                a0 = fmaf(hv.x, wc[4 * kk + 0], a0);
                a1 = fmaf(hv.y, wc[4 * kk + 1], a1);
                a2 = fmaf(hv.z, wc[4 * kk + 2], a2);
                a3 = fmaf(hv.w, wc[4 * kk + 3], a3);
            }
            ph[half][u] = (a0 + a1) + (a2 + a3);
        }
        bar_lds();   // ph ready

        // Phase C2: h update (grp 4 only)
        if (grp == 4) {
            float mv2 = ph[0][u] + ph[1][u];
            float hb = tanhf(c0 + mv2);
            float hf = tanhf(hb + c1);
            float hc = (1.f - c2) * hb + c2 * hf;
            float z  = zb[u];
            hn = (1.f - z) * hd[u] + z * hc;   // alpha==1 -> h_att = h_d
            hd[u] = c3 * hn;                    // decay[s+1] * h_new
        }
        bar_lds();   // hd ready for next step

        c0 = n0; c1 = n1; c2 = n2; c3 = n3;
    }
    if (grp == 4) Hb[(size_t)b * U_ + u] = f2bf(hn);
}

// ---------------------------------------------------------------------------
// k4a: logits = h @ W_out + b_out via bf16 MFMA.
__global__ __launch_bounds__(256) void k4a_logits(
    const unsigned short* __restrict__ Hb, const unsigned short* __restrict__ WT,
    const float* __restrict__ b_out, float* __restrict__ logits)
{
    const int tid  = threadIdx.x;
    const int lane = tid & 63, wid = tid >> 6;
    const int quad = lane >> 4, l16 = lane & 15;
    const int rb = blockIdx.y * 64 + wid * 16;
    const int cb = blockIdx.x * 128;

    short8v av[4];
#pragma unroll
    for (int kb = 0; kb < 4; ++kb)
        av[kb] = *(const short8v*)&Hb[(size_t)(rb + l16) * 128 + kb * 32 + quad * 8];

    float4v acc[8];
#pragma unroll
    for (int i = 0; i < 8; ++i) acc[i] = (float4v)0.0f;

#pragma unroll
    for (int kb = 0; kb < 4; ++kb) {
#pragma unroll
        for (int nt = 0; nt < 8; ++nt) {
            short8v bv = *(const short8v*)&WT[(size_t)(cb + nt * 16 + l16) * 128 + kb * 32 + quad * 8];
            acc[nt] = __builtin_amdgcn_mfma_f32_16x16x32_bf16(av[kb], bv, acc[nt], 0, 0, 0);
        }
    }
#pragma unroll
    for (int nt = 0; nt < 8; ++nt) {
        int n = cb + nt * 16 + l16;
        if (n < NC) {
            float bb = b_out[n];
#pragma unroll
            for (int r = 0; r < 4; ++r)
                logits[(size_t)(rb + quad * 4 + r) * NC + n] = acc[nt][r] + bb;
        }
    }
}

// ---------------------------------------------------------------------------
__global__ __launch_bounds__(256) void k4b_rowstats(
    const float* __restrict__ logits, float* __restrict__ rmax, float* __restrict__ rsum)
{
    const int r = blockIdx.x;
    const int tid = threadIdx.x;
    const float* row = logits + (size_t)r * NC;

    float m = -INFINITY, s = 0.f;
    for (int c = tid; c < NC; c += 256) {
        float x = row[c];
        float mn = fmaxf(m, x);
        s = s * expf(m - mn) + expf(x - mn);
        m = mn;
    }
    __shared__ float sm[256], ss[256];
    sm[tid] = m; ss[tid] = s;
    __syncthreads();
    for (int off = 128; off > 0; off >>= 1) {
        if (tid < off) {
            float m2 = sm[tid + off], s2 = ss[tid + off];
            float M = fmaxf(sm[tid], m2);
            ss[tid] = ss[tid] * expf(sm[tid] - M) + s2 * expf(m2 - M);
            sm[tid] = M;
        }
        __syncthreads();
    }
    if (tid == 0) { rmax[r] = sm[0]; rsum[r] = ss[0]; }
}

__global__ __launch_bounds__(256) void k4c_norm(
    const float* __restrict__ logits, const float* __restrict__ rmax,
    const float* __restrict__ rsum, float* __restrict__ out)
{
    const int r = blockIdx.y;
    const int c = blockIdx.x * 256 + threadIdx.x;
    if (c < NC) {
        size_t i = (size_t)r * NC + c;
        out[i] = expf(logits[i] - rmax[r]) / rsum[r];
    }
}

// ---------------------------------------------------------------------------
extern "C" void kernel_launch(void* const* d_in, const int* in_sizes, int n_in,
                              void* d_out, int out_size, void* d_ws, size_t ws_size,
                              hipStream_t stream) {
    const int*   item   = (const int*)d_in[0];
    const int*   tix    = (const int*)d_in[1];
    const int*   frq    = (const int*)d_in[2];
    const float* Ei     = (const float*)d_in[3];
    const float* Et     = (const float*)d_in[4];
    const float* Ef     = (const float*)d_in[5];
    const float* W_xr   = (const float*)d_in[6];
    const float* W_hr   = (const float*)d_in[7];
    const float* b_r    = (const float*)d_in[8];
    const float* W_xz   = (const float*)d_in[9];
    const float* W_hz   = (const float*)d_in[10];
    const float* b_z    = (const float*)d_in[11];
    const float* W_xh   = (const float*)d_in[12];
    const float* W_hh   = (const float*)d_in[13];
    const float* b_h    = (const float*)d_in[14];
    const float* W_xtg  = (const float*)d_in[15];
    const float* W_tg   = (const float*)d_in[16];
    const float* b_tg   = (const float*)d_in[17];
    const float* W_xfg  = (const float*)d_in[18];
    const float* W_fg   = (const float*)d_in[19];
    const float* b_fg   = (const float*)d_in[20];
    const float* W_delta= (const float*)d_in[21];
    const float* b_delta= (const float*)d_in[22];
    const float* W_f_dir= (const float*)d_in[23];
    const float* b_f_dir= (const float*)d_in[24];
    const float* W_psi  = (const float*)d_in[25];
    const float* b_psi  = (const float*)d_in[26];
    // d_in[27] = W_a — dead (softmax over singleton axis == 1)
    const float* W_out  = (const float*)d_in[28];
    const float* b_out  = (const float*)d_in[29];
    float* out = (float*)d_out;

    float* ws   = (float*)d_ws;
    float* PRE  = ws + PRE_OFF;
    float* LOG  = ws + LOG_OFF;
    unsigned short* WSWZ = (unsigned short*)(ws + WSWZ_OFF);
    unsigned short* WT   = (unsigned short*)(ws + PRE_OFF);   // aliases PRE (dead after k3)
    unsigned short* Hb   = (unsigned short*)(ws + HF_OFF);
    float* RMAX = ws + RMAX_OFF;
    float* RSUM = ws + RSUM_OFF;

    k0_wconv<<<12, 256, 0, stream>>>(
        W_xtg, W_tg, W_xfg, W_fg, W_xr, W_xz, W_xh,
        W_delta, W_delta + 128 * 128, W_f_dir, W_psi,
        W_psi /* pad slot 11, unused by k12 */, WSWZ);
    k12_precompute<<<NTOK / 64, 256, 0, stream>>>(
        item, tix, frq, Ei, Et, Ef,
        b_r, b_z, b_h, b_tg, b_fg, b_delta, b_f_dir, b_psi,
        WSWZ, PRE);
    k3_scan<<<B_, 768, 0, stream>>>(PRE, W_hr, W_hz, W_hh, Hb);
    k0b_woutT<<<(NC + 63) / 64, 256, 0, stream>>>(W_out, WT);
    k4a_logits<<<dim3((NC + 127) / 128, B_ / 64), 256, 0, stream>>>(Hb, WT, b_out, LOG);
    k4b_rowstats<<<B_, 256, 0, stream>>>(LOG, RMAX, RSUM);
    k4c_norm<<<dim3((NC + 255) / 256, B_), 256, 0, stream>>>(LOG, RMAX, RSUM, out);
}